// Round 3
// baseline (90.677 us; speedup 1.0000x reference)
//
#include <hip/hip_runtime.h>
#include <hip/hip_bf16.h>

#define NB   4
#define NC   2
#define NS   4096
#define NOUT 512
#define UPAD 80    // stored u-stride in workspace (u<65 consumed)
#define MT   128   // o rows per block in GEMM

typedef short  short8_t  __attribute__((ext_vector_type(8)));
typedef float  float16_t __attribute__((ext_vector_type(16)));

__device__ __forceinline__ short bf16s(float f) {
    union { __hip_bfloat16 b; short s; } u;
    u.b = __float2bfloat16(f);   // RNE
    return u.s;
}
__device__ __forceinline__ float s2f(unsigned short s) {
    union { unsigned int u; float f; } v;
    v.u = ((unsigned int)s) << 16;
    return v.f;
}

// ---------------------------------------------------------------------------
// Kernel A: split-K GEMM partials (bf16 output).
//   H[b,o,u] = sum_k conv_w[o,k] * Xs[k,u],  Xs[2048c+t,u] = xp[b,c,2t+u]
//   Block: 128 o-rows x 96 u-cols (u>=80 dropped) x KC k.  Grid = NB*4*KCN.
//   B-trick: xe[i]=xp[2i], xo[i]=xp[2i+1]; Xs[k][u]=(u&1?xo:xe)[k+(u>>1)];
//   8 shifted LDS copies per parity -> every B-fragment is one ds_read_b128.
//   K-loop fully unrolled so all A-loads issue up front (one latency wave).
// ---------------------------------------------------------------------------
template<int KCN>
__global__ __launch_bounds__(256)
void gemm_partials(const float* __restrict__ x,
                   const float* __restrict__ conv_w,
                   unsigned short* __restrict__ hpart)
{
    constexpr int KC  = 4096 / KCN;
    constexpr int XSZ = KC + 56;
    __shared__ __align__(16) short xS[16][XSZ];

    const int blk = blockIdx.x;
    const int kc  = blk % KCN;
    const int ot  = (blk / KCN) & 3;
    const int b   = blk / (KCN * 4);

    const int K0 = kc * KC;
    const int c  = K0 >> 11;
    const int tb = K0 & 2047;

    const int tid = threadIdx.x;
    const float* xc = x + (size_t)(b * NC + c) * NS;

    for (int i = tid; i < XSZ; i += 256) {
        int ge = (tb + i) * 2;
        float fe = (ge     < NS) ? xc[ge]     : 0.0f;
        float fo = (ge + 1 < NS) ? xc[ge + 1] : 0.0f;
        short se = bf16s(fe), so = bf16s(fo);
        #pragma unroll
        for (int r = 0; r < 8; ++r) {
            int j = i - r;
            if (j >= 0) { xS[r][j] = se; xS[8 + r][j] = so; }
        }
    }
    __syncthreads();

    const int wave = tid >> 6;
    const int lane = tid & 63;
    const int l31  = lane & 31;
    const int q    = lane >> 5;
    const int kq   = q * 8;

    const float* wrow = conv_w + (size_t)(ot * MT + wave * 32 + l31) * 4096 + K0;

    float16_t acc[3];
    #pragma unroll
    for (int nt = 0; nt < 3; ++nt)
        #pragma unroll
        for (int e = 0; e < 16; ++e) acc[nt][e] = 0.0f;

    int arr[3], hb[3];
    #pragma unroll
    for (int nt = 0; nt < 3; ++nt) {
        int uu = nt * 32 + l31;
        int h  = uu >> 1;
        arr[nt] = (uu & 1) * 8 + (h & 7);
        hb[nt]  = h & ~7;
    }

    #pragma unroll
    for (int step = 0; step < KC / 16; ++step) {
        const int kl = step * 16 + kq;
        float4 a0 = *(const float4*)(wrow + kl);
        float4 a1 = *(const float4*)(wrow + kl + 4);
        short8_t af = { bf16s(a0.x), bf16s(a0.y), bf16s(a0.z), bf16s(a0.w),
                        bf16s(a1.x), bf16s(a1.y), bf16s(a1.z), bf16s(a1.w) };
        #pragma unroll
        for (int nt = 0; nt < 3; ++nt) {
            short8_t bf = *(const short8_t*)&xS[arr[nt]][kl + hb[nt]];
            acc[nt] = __builtin_amdgcn_mfma_f32_32x32x16_bf16(af, bf, acc[nt], 0, 0, 0);
        }
    }

    // D layout: col=lane&31 (u), row=(reg&3)+8*(reg>>2)+4*q
    unsigned short* hp = hpart + (size_t)(kc * NB + b) * NOUT * UPAD;
    #pragma unroll
    for (int nt = 0; nt < 3; ++nt) {
        int uu = nt * 32 + l31;
        if (uu < UPAD) {
            #pragma unroll
            for (int reg = 0; reg < 16; ++reg) {
                int row = (reg & 3) + 8 * (reg >> 2) + 4 * q;
                int o   = ot * MT + wave * 32 + row;
                hp[(size_t)o * UPAD + uu] = (unsigned short)bf16s(acc[nt][reg]);
            }
        }
    }
}

// ---------------------------------------------------------------------------
// Kernel B: sum bf16 split-K partials -> H[65], then epilogue:
//   out[b,o,2048r+32m+l] = relu(stft_w[l,m]*H[r+m] + conv_b[o])
// ---------------------------------------------------------------------------
template<int KCN>
__global__ __launch_bounds__(256)
void reduce_epilogue(const unsigned short* __restrict__ hpart,
                     const float* __restrict__ stft_w,
                     const float* __restrict__ conv_b,
                     float* __restrict__ out)
{
    __shared__ float Hs[65];
    const int tid = threadIdx.x;
    const int bid = blockIdx.x;
    const int b = bid >> 9;
    const int o = bid & 511;

    if (tid < 65) {
        const unsigned short* hp0 = hpart + ((size_t)b * NOUT + o) * UPAD + tid;
        float h = 0.0f;
        #pragma unroll
        for (int s = 0; s < KCN; ++s)
            h += s2f(hp0[(size_t)s * NB * NOUT * UPAD]);
        Hs[tid] = h;
    }
    __syncthreads();

    const float bias = conv_b[o];
    float* ob = out + (size_t)(b * NOUT + o) * NS;
    #pragma unroll
    for (int it = 0; it < 4; ++it) {
        int s4 = (it * 256 + tid) * 4;
        int r  = s4 >> 11;
        int qq = s4 & 2047;
        int m  = qq >> 5;
        int l  = qq & 31;
        float h = Hs[r + m];
        float v0 = fmaf(stft_w[(l + 0) * 64 + m], h, bias);
        float v1 = fmaf(stft_w[(l + 1) * 64 + m], h, bias);
        float v2 = fmaf(stft_w[(l + 2) * 64 + m], h, bias);
        float v3 = fmaf(stft_w[(l + 3) * 64 + m], h, bias);
        float4 res;
        res.x = v0 > 0.0f ? v0 : 0.0f;
        res.y = v1 > 0.0f ? v1 : 0.0f;
        res.z = v2 > 0.0f ? v2 : 0.0f;
        res.w = v3 > 0.0f ? v3 : 0.0f;
        *(float4*)(ob + s4) = res;
    }
}

// ---------------------------------------------------------------------------
template<int KCN>
static void launch_pair(const float* x, const float* stft_w, const float* conv_w,
                        const float* conv_b, float* out, unsigned short* ws,
                        hipStream_t stream)
{
    gemm_partials<KCN><<<dim3(NB * 4 * KCN), dim3(256), 0, stream>>>(x, conv_w, ws);
    reduce_epilogue<KCN><<<dim3(NB * NOUT), dim3(256), 0, stream>>>(ws, stft_w, conv_b, out);
}

extern "C" void kernel_launch(void* const* d_in, const int* in_sizes, int n_in,
                              void* d_out, int out_size, void* d_ws, size_t ws_size,
                              hipStream_t stream) {
    const float* x      = (const float*)d_in[0];
    const float* stft_w = (const float*)d_in[1];
    const float* conv_w = (const float*)d_in[2];
    const float* conv_b = (const float*)d_in[3];
    float* out = (float*)d_out;
    unsigned short* ws = (unsigned short*)d_ws;

    const size_t per_slice = (size_t)NB * NOUT * UPAD * sizeof(unsigned short); // 327680 B
    if      (ws_size >= 32 * per_slice) launch_pair<32>(x, stft_w, conv_w, conv_b, out, ws, stream);
    else if (ws_size >= 16 * per_slice) launch_pair<16>(x, stft_w, conv_w, conv_b, out, ws, stream);
    else if (ws_size >=  8 * per_slice) launch_pair<8 >(x, stft_w, conv_w, conv_b, out, ws, stream);
    else                                launch_pair<4 >(x, stft_w, conv_w, conv_b, out, ws, stream);
}

// Round 5
// 88.278 us; speedup vs baseline: 1.0272x; 1.0272x over previous
//
#include <hip/hip_runtime.h>
#include <hip/hip_bf16.h>

#define NB   4
#define NC   2
#define NS   4096
#define NOUT 512
#define UPAD 80    // stored u-stride in workspace (u<65 consumed)

typedef short  short8_t  __attribute__((ext_vector_type(8)));
typedef short  short4_t  __attribute__((ext_vector_type(4)));
typedef float  float16_t __attribute__((ext_vector_type(16)));

__device__ __forceinline__ short bf16s(float f) {
    union { __hip_bfloat16 b; short s; } u;
    u.b = __float2bfloat16(f);   // RNE
    return u.s;
}
__device__ __forceinline__ float s2f(unsigned short s) {
    union { unsigned int u; float f; } v;
    v.u = ((unsigned int)s) << 16;
    return v.f;
}

// ---------------------------------------------------------------------------
// Kernel A: split-K GEMM partials (bf16 out).
//   H[b,o,u] = sum_k conv_w[o,k] * Xs[k,u],  Xs[2048c+t,u] = xp[b,c,2t+u]
//   Block: 128 o x 96 u (u>=80 dropped) x KC k.  Grid = NB*4*KCN.
//   A-path: conv_w tile staged to LDS with COALESCED loads (32 lanes sweep
//   one row -> 16 lines/inst vs 64-line gather), bf16 in LDS, fragments via
//   ds_read_b128. Row stride KC+8 shorts (16B-aligned rows; 4-way conflict
//   on A-reads, ~free).
//   B-path (validated R2/R3): xe/xo + 8 shifted copies -> ds_read_b128.
//   XSZ = KC+56: copy r covers j <= XSZ-1-r; max read j = KC+39, r = 7
//   -> need XSZ >= KC+47 (KC+40 in R4 was a bug).
//   LDS fits only for KCN >= 8 — do not instantiate smaller.
// ---------------------------------------------------------------------------
template<int KCN>
__global__ __launch_bounds__(256)
void gemm_partials(const float* __restrict__ x,
                   const float* __restrict__ conv_w,
                   unsigned short* __restrict__ hpart)
{
    constexpr int KC      = 4096 / KCN;
    constexpr int XSZ     = KC + 56;
    constexpr int ASTRIDE = KC + 8;       // shorts; (KC+8)*2 % 16 == 0
    static_assert(KCN >= 8, "A-tile LDS exceeds 160KB below KCN=8");

    __shared__ __align__(16) short aS[128 * ASTRIDE];
    __shared__ __align__(16) short xS[16][XSZ];

    const int blk = blockIdx.x;
    const int kc  = blk % KCN;
    const int ot  = (blk / KCN) & 3;
    const int b   = blk / (KCN * 4);

    const int K0 = kc * KC;
    const int c  = K0 >> 11;
    const int tb = K0 & 2047;
    const int tid = threadIdx.x;

    // ---- stage B: even/odd parities, 8 shifted copies each ----
    const float* xc = x + (size_t)(b * NC + c) * NS;
    for (int i = tid; i < XSZ; i += 256) {
        int ge = (tb + i) * 2;
        float fe = (ge     < NS) ? xc[ge]     : 0.0f;
        float fo = (ge + 1 < NS) ? xc[ge + 1] : 0.0f;
        short se = bf16s(fe), so = bf16s(fo);
        #pragma unroll
        for (int r = 0; r < 8; ++r) {
            int j = i - r;
            if (j >= 0) { xS[r][j] = se; xS[8 + r][j] = so; }
        }
    }

    // ---- stage A: coalesced fp32 reads, bf16 to LDS ----
    {
        const int rr = tid >> 5;            // 0..7
        const int cc = (tid & 31) * 4;      // 0..124 within 128-col chunk
        const float* wbase = conv_w + (size_t)(ot * 128) * 4096 + K0;
        #pragma unroll
        for (int cb = 0; cb < KC; cb += 128) {
            #pragma unroll
            for (int it = 0; it < 16; ++it) {
                int row = it * 8 + rr;
                float4 v = *(const float4*)(wbase + (size_t)row * 4096 + cb + cc);
                short4_t p = { bf16s(v.x), bf16s(v.y), bf16s(v.z), bf16s(v.w) };
                *(short4_t*)&aS[row * ASTRIDE + cb + cc] = p;
            }
        }
    }
    __syncthreads();

    const int wave = tid >> 6;
    const int lane = tid & 63;
    const int l31  = lane & 31;
    const int q    = lane >> 5;

    const short* arow = &aS[(wave * 32 + l31) * ASTRIDE];

    float16_t acc[3];
    #pragma unroll
    for (int nt = 0; nt < 3; ++nt)
        #pragma unroll
        for (int e = 0; e < 16; ++e) acc[nt][e] = 0.0f;

    int arr[3], hb[3];
    #pragma unroll
    for (int nt = 0; nt < 3; ++nt) {
        int uu = nt * 32 + l31;
        int h  = uu >> 1;
        arr[nt] = (uu & 1) * 8 + (h & 7);
        hb[nt]  = h & ~7;
    }

    #pragma unroll
    for (int step = 0; step < KC / 16; ++step) {
        const int kl = step * 16 + q * 8;
        short8_t af = *(const short8_t*)(arow + kl);
        #pragma unroll
        for (int nt = 0; nt < 3; ++nt) {
            short8_t bf = *(const short8_t*)&xS[arr[nt]][kl + hb[nt]];
            acc[nt] = __builtin_amdgcn_mfma_f32_32x32x16_bf16(af, bf, acc[nt], 0, 0, 0);
        }
    }

    // D layout (validated): col=lane&31 (u), row=(reg&3)+8*(reg>>2)+4*q
    unsigned short* hp = hpart + (size_t)(kc * NB + b) * NOUT * UPAD;
    #pragma unroll
    for (int nt = 0; nt < 3; ++nt) {
        int uu = nt * 32 + l31;
        if (uu < UPAD) {
            #pragma unroll
            for (int reg = 0; reg < 16; ++reg) {
                int row = (reg & 3) + 8 * (reg >> 2) + 4 * q;
                int o   = ot * 128 + wave * 32 + row;
                hp[(size_t)o * UPAD + uu] = (unsigned short)bf16s(acc[nt][reg]);
            }
        }
    }
}

// ---------------------------------------------------------------------------
// Kernel B: sum bf16 split-K partials -> H[65] (loads split over 2 waves),
// then validated epilogue:
//   out[b,o,2048r+32m+l] = relu(stft_w[l,m]*H[r+m] + conv_b[o])
// ---------------------------------------------------------------------------
template<int KCN>
__global__ __launch_bounds__(256)
void reduce_epilogue(const unsigned short* __restrict__ hpart,
                     const float* __restrict__ stft_w,
                     const float* __restrict__ conv_b,
                     float* __restrict__ out)
{
    __shared__ float HsA[65], HsB[65];
    const int tid = threadIdx.x;
    const int bid = blockIdx.x;
    const int b = bid >> 9;
    const int o = bid & 511;

    constexpr int HALF = KCN / 2;
    const size_t slice = (size_t)NB * NOUT * UPAD;

    if (tid < 65) {                       // waves 0/1: slices [0, HALF)
        const unsigned short* hp0 = hpart + ((size_t)b * NOUT + o) * UPAD + tid;
        float h = 0.0f;
        #pragma unroll
        for (int s = 0; s < HALF; ++s) h += s2f(hp0[(size_t)s * slice]);
        HsA[tid] = h;
    } else if (tid >= 128 && tid < 193) { // wave 2: slices [HALF, KCN)
        const unsigned short* hp0 = hpart + ((size_t)b * NOUT + o) * UPAD + (tid - 128)
                                  + (size_t)HALF * slice;
        float h = 0.0f;
        #pragma unroll
        for (int s = 0; s < KCN - HALF; ++s) h += s2f(hp0[(size_t)s * slice]);
        HsB[tid - 128] = h;
    }
    __syncthreads();

    const float bias = conv_b[o];
    float* ob = out + (size_t)(b * NOUT + o) * NS;
    #pragma unroll
    for (int it = 0; it < 4; ++it) {
        int s4 = (it * 256 + tid) * 4;
        int r  = s4 >> 11;
        int qq = s4 & 2047;
        int m  = qq >> 5;
        int l  = qq & 31;
        float h = HsA[r + m] + HsB[r + m];
        float v0 = fmaf(stft_w[(l + 0) * 64 + m], h, bias);
        float v1 = fmaf(stft_w[(l + 1) * 64 + m], h, bias);
        float v2 = fmaf(stft_w[(l + 2) * 64 + m], h, bias);
        float v3 = fmaf(stft_w[(l + 3) * 64 + m], h, bias);
        float4 res;
        res.x = v0 > 0.0f ? v0 : 0.0f;
        res.y = v1 > 0.0f ? v1 : 0.0f;
        res.z = v2 > 0.0f ? v2 : 0.0f;
        res.w = v3 > 0.0f ? v3 : 0.0f;
        *(float4*)(ob + s4) = res;
    }
}

// ---------------------------------------------------------------------------
// Fallback (no workspace): the R1 fused kernel — validated, ~45 us. Should
// never run given observed ws_size >= 10.5 MB, but guarantees correctness.
// ---------------------------------------------------------------------------
__device__ __forceinline__ int swz(int i) { return i + (i >> 5); }

__global__ __launch_bounds__(256, 3)
void fused_cnn(const float* __restrict__ x,
               const float* __restrict__ stft_w,
               const float* __restrict__ conv_w,
               const float* __restrict__ conv_b,
               float* __restrict__ out)
{
    __shared__ float xs[2 * 4290];
    __shared__ float ws_[4224];
    __shared__ float Hs[65];

    const int tid = threadIdx.x;
    const int bid = blockIdx.x;
    const int b = bid >> 9;
    const int o = bid & 511;

    for (int c = 0; c < NC; ++c) {
        const float* xb = x + (size_t)(b * NC + c) * NS;
        float* dst = xs + c * 4290;
        #pragma unroll
        for (int it = 0; it < 4; ++it) {
            int i0 = (it * 256 + tid) * 4;
            float4 v = *(const float4*)(xb + i0);
            dst[swz(i0 + 0)] = v.x; dst[swz(i0 + 1)] = v.y;
            dst[swz(i0 + 2)] = v.z; dst[swz(i0 + 3)] = v.w;
        }
        if (tid < 64) dst[swz(4096 + tid)] = 0.0f;
    }
    {
        const float* wrow = conv_w + (size_t)o * 4096;
        #pragma unroll
        for (int it = 0; it < 4; ++it) {
            int i0 = (it * 256 + tid) * 4;
            float4 v = *(const float4*)(wrow + i0);
            ws_[swz(i0 + 0)] = v.x; ws_[swz(i0 + 1)] = v.y;
            ws_[swz(i0 + 2)] = v.z; ws_[swz(i0 + 3)] = v.w;
        }
    }
    __syncthreads();

    const int wave = tid >> 6;
    const int lane = tid & 63;
    const int u0 = wave << 4;

    float acc[17];
    #pragma unroll
    for (int i = 0; i < 17; ++i) acc[i] = 0.0f;

    for (int g = 0; g < 8; ++g) {
        int G = lane + (g << 6);
        int c = G >> 8;
        int t0 = (G & 255) << 3;
        int wb = c * 2048 + t0;
        float w[8];
        #pragma unroll
        for (int j = 0; j < 8; ++j) w[j] = ws_[swz(wb + j)];
        const float* xcs = xs + c * 4290;
        int xb0 = 2 * t0 + u0;
        #pragma unroll
        for (int d = 0; d <= 30; ++d) {
            float xv = xcs[swz(xb0 + d)];
            #pragma unroll
            for (int j = 0; j < 8; ++j) {
                int uu = d - 2 * j;
                if (uu >= 0 && uu < 17) acc[uu] += w[j] * xv;
            }
        }
    }
    #pragma unroll
    for (int uu = 0; uu < 17; ++uu) {
        float v = acc[uu];
        #pragma unroll
        for (int off = 1; off < 64; off <<= 1) v += __shfl_xor(v, off, 64);
        acc[uu] = v;
    }
    if (lane == 0)
        #pragma unroll
        for (int uu = 0; uu < 17; ++uu)
            if (uu < 16 || wave == 3) Hs[u0 + uu] = acc[uu];
    __syncthreads();

    const float bias = conv_b[o];
    float* ob = out + (size_t)(b * NOUT + o) * NS;
    #pragma unroll
    for (int it = 0; it < 4; ++it) {
        int s4 = (it * 256 + tid) * 4;
        int r = s4 >> 11;
        int qq = s4 & 2047;
        int m = qq >> 5;
        int l = qq & 31;
        float h = Hs[r + m];
        float v0 = fmaf(stft_w[(l + 0) * 64 + m], h, bias);
        float v1 = fmaf(stft_w[(l + 1) * 64 + m], h, bias);
        float v2 = fmaf(stft_w[(l + 2) * 64 + m], h, bias);
        float v3 = fmaf(stft_w[(l + 3) * 64 + m], h, bias);
        float4 res;
        res.x = v0 > 0.0f ? v0 : 0.0f;
        res.y = v1 > 0.0f ? v1 : 0.0f;
        res.z = v2 > 0.0f ? v2 : 0.0f;
        res.w = v3 > 0.0f ? v3 : 0.0f;
        *(float4*)(ob + s4) = res;
    }
}

// ---------------------------------------------------------------------------
template<int KCN>
static void launch_pair(const float* x, const float* stft_w, const float* conv_w,
                        const float* conv_b, float* out, unsigned short* ws,
                        hipStream_t stream)
{
    gemm_partials<KCN><<<dim3(NB * 4 * KCN), dim3(256), 0, stream>>>(x, conv_w, ws);
    reduce_epilogue<KCN><<<dim3(NB * NOUT), dim3(256), 0, stream>>>(ws, stft_w, conv_b, out);
}

extern "C" void kernel_launch(void* const* d_in, const int* in_sizes, int n_in,
                              void* d_out, int out_size, void* d_ws, size_t ws_size,
                              hipStream_t stream) {
    const float* x      = (const float*)d_in[0];
    const float* stft_w = (const float*)d_in[1];
    const float* conv_w = (const float*)d_in[2];
    const float* conv_b = (const float*)d_in[3];
    float* out = (float*)d_out;
    unsigned short* ws = (unsigned short*)d_ws;

    const size_t per_slice = (size_t)NB * NOUT * UPAD * sizeof(unsigned short); // 327680 B
    if      (ws_size >= 32 * per_slice) launch_pair<32>(x, stft_w, conv_w, conv_b, out, ws, stream);
    else if (ws_size >= 16 * per_slice) launch_pair<16>(x, stft_w, conv_w, conv_b, out, ws, stream);
    else if (ws_size >=  8 * per_slice) launch_pair<8 >(x, stft_w, conv_w, conv_b, out, ws, stream);
    else
        fused_cnn<<<dim3(NB * NOUT), dim3(256), 0, stream>>>(x, stft_w, conv_w, conv_b, out);
}